// Round 1
// baseline (965.235 us; speedup 1.0000x reference)
//
#include <hip/hip_runtime.h>
#include <math.h>

#define B_    4
#define L_    4096
#define DM    128
#define DI    256
#define DS    16
#define DTR   8
#define XPN   (DTR + 2*DS)   // 40
#define NB    (DI + 2*DS)    // 288 fused xproj output cols
#define M_    (B_*L_)        // 16384
#define CHUNK 32
#define NC    (L_/CHUNK)     // 128
#define LOG2E 1.4426950408889634f
#define PREP_N (512*128 + NB*DI + DM*DI)   // 172032

typedef __attribute__((ext_vector_type(8))) short bf16x8;   // 8 bf16 = 4 VGPR
typedef __attribute__((ext_vector_type(4))) float f32x4;    // MFMA acc
typedef unsigned short ushort_t;

__device__ __forceinline__ ushort_t f2bf(float f) {  // fp32 -> bf16 RNE
  unsigned int u = __float_as_uint(f);
  u += 0x7FFFu + ((u >> 16) & 1u);
  return (ushort_t)(u >> 16);
}
__device__ __forceinline__ float bf2f(ushort_t u) {
  return __uint_as_float(((unsigned int)u) << 16);
}

// ---------------- prep (weights->bf16 transposed, dtproj folded) + rmsnorm ----
// Also zeroes the ticket + lookback flags (workspace is poisoned between runs).
__global__ __launch_bounds__(256) void prep_rms_kernel(const float* __restrict__ x,
                                                       const float* __restrict__ nw,
                                                       const float* __restrict__ inW,
                                                       const float* __restrict__ Wx,
                                                       const float* __restrict__ Wdt,
                                                       const float* __restrict__ outw,
                                                       ushort_t* __restrict__ xbf,
                                                       ushort_t* __restrict__ inWt,
                                                       ushort_t* __restrict__ WbigT,
                                                       ushort_t* __restrict__ outWt,
                                                       unsigned int* __restrict__ syncb) {
  if (blockIdx.x == 0) {
    for (int i = threadIdx.x; i < 520; i += 256) syncb[i] = 0u;
  }
  if (blockIdx.x < M_ / 4) {  // rmsnorm -> bf16
    int row  = blockIdx.x * 4 + (threadIdx.x >> 6);
    int lane = threadIdx.x & 63;
    const float* xp = x + (size_t)row * DM;
    float v0 = xp[lane], v1 = xp[lane + 64];
    float s = v0 * v0 + v1 * v1;
    #pragma unroll
    for (int off = 32; off > 0; off >>= 1) s += __shfl_xor(s, off);
    float r = rsqrtf(s / DM + 1e-5f);
    ushort_t* op = xbf + (size_t)row * DM;
    op[lane]      = f2bf(v0 * r * nw[lane]);
    op[lane + 64] = f2bf(v1 * r * nw[lane + 64]);
    return;
  }
  int g = (blockIdx.x - M_ / 4) * 256 + threadIdx.x;
  if (g < 512 * 128) {
    int n = g >> 7, k = g & 127;
    inWt[g] = f2bf(inW[k * 512 + n]);
  } else if (g < 512 * 128 + NB * DI) {
    int q = g - 512 * 128;
    int c = q >> 8, k = q & 255;
    float v;
    if (c < DI) {
      v = 0.f;
      #pragma unroll
      for (int j = 0; j < DTR; ++j) v = fmaf(Wx[k * XPN + j], Wdt[j * DI + c], v);
    } else {
      v = Wx[k * XPN + DTR + (c - DI)];
    }
    WbigT[q] = f2bf(v);
  } else if (g < PREP_N) {
    int q = g - (512 * 128 + NB * DI);
    int n = q >> 8, k = q & 255;
    outWt[q] = f2bf(outw[k * DM + n]);
  }
}

// ---------------- G1 fused: in_proj MFMA + depthwise conv + SiLU -------------
__global__ __launch_bounds__(256) void g1_conv_kernel(const ushort_t* __restrict__ A,
                                                      const ushort_t* __restrict__ Wt,
                                                      const float* __restrict__ cw,
                                                      const float* __restrict__ cb,
                                                      ushort_t* __restrict__ xcbf,
                                                      ushort_t* __restrict__ resbf) {
  constexpr int KK = 128, NT = 4;
  __shared__ __align__(16) char smem_raw[35648];
  ushort_t (*Asm)[145][8] = (ushort_t (*)[145][8])smem_raw;          // 18560 B
  ushort_t (*Bx)[65][8]   = (ushort_t (*)[65][8])(smem_raw + 18560); //  8320 B
  ushort_t (*Br)[65][8]   = (ushort_t (*)[65][8])(smem_raw + 26880); //  8320 B
  float* T = (float*)smem_raw;                                       // [131][68]
  const int tid  = threadIdx.x;
  const int wave = tid >> 6, lane = tid & 63;
  const int quad = lane >> 4, l16 = lane & 15;
  const int row0 = blockIdx.x * 128;
  const int by   = blockIdx.y;          // 0..3
  const int c0x  = by * 64;             // xi cols
  const int c0r  = 256 + by * 64;       // res cols (global N index)
  const bool zpad = (row0 & (L_ - 1)) == 0;
  f32x4 ax[2][NT], ar[2][NT], acc2[NT];
  #pragma unroll
  for (int mt = 0; mt < 2; ++mt)
    #pragma unroll
    for (int nt = 0; nt < NT; ++nt) {
      ax[mt][nt] = (f32x4){0.f, 0.f, 0.f, 0.f};
      ar[mt][nt] = (f32x4){0.f, 0.f, 0.f, 0.f};
    }
  #pragma unroll
  for (int nt = 0; nt < NT; ++nt) acc2[nt] = (f32x4){0.f, 0.f, 0.f, 0.f};

  for (int k0 = 0; k0 < KK; k0 += 64) {
    #pragma unroll
    for (int i = 0; i < 5; ++i) {  // A: 144 rows x 64 bf16 = 1152 b128
      int q = tid + i * 256;
      if (i < 4 || tid < 128) {
        int m = q >> 3, kb = q & 7;
        bf16x8 v = {0, 0, 0, 0, 0, 0, 0, 0};
        if (!(zpad && m < 16))
          v = *(const bf16x8*)(A + (size_t)(row0 - 16 + m) * KK + k0 + kb * 8);
        *(bf16x8*)(&Asm[kb][m][0]) = v;
      }
    }
    #pragma unroll
    for (int i = 0; i < 2; ++i) {  // B xi: 64x64 bf16
      int q = tid + i * 256;
      int n = q >> 3, kb = q & 7;
      *(bf16x8*)(&Bx[kb][n][0]) =
          *(const bf16x8*)(Wt + (size_t)(c0x + n) * KK + k0 + kb * 8);
    }
    #pragma unroll
    for (int i = 0; i < 2; ++i) {  // B res: 64x64 bf16
      int q = tid + i * 256;
      int n = q >> 3, kb = q & 7;
      *(bf16x8*)(&Br[kb][n][0]) =
          *(const bf16x8*)(Wt + (size_t)(c0r + n) * KK + k0 + kb * 8);
    }
    __syncthreads();
    #pragma unroll
    for (int ks = 0; ks < 2; ++ks) {
      bf16x8 af[2], bx[NT], br[NT];
      #pragma unroll
      for (int mt = 0; mt < 2; ++mt)
        af[mt] = *(const bf16x8*)(&Asm[ks * 4 + quad][16 + wave * 32 + mt * 16 + l16][0]);
      #pragma unroll
      for (int nt = 0; nt < NT; ++nt) {
        bx[nt] = *(const bf16x8*)(&Bx[ks * 4 + quad][nt * 16 + l16][0]);
        br[nt] = *(const bf16x8*)(&Br[ks * 4 + quad][nt * 16 + l16][0]);
      }
      #pragma unroll
      for (int mt = 0; mt < 2; ++mt)
        #pragma unroll
        for (int nt = 0; nt < NT; ++nt) {
          ax[mt][nt] = __builtin_amdgcn_mfma_f32_16x16x32_bf16(af[mt], bx[nt],
                                                               ax[mt][nt], 0, 0, 0);
          ar[mt][nt] = __builtin_amdgcn_mfma_f32_16x16x32_bf16(af[mt], br[nt],
                                                               ar[mt][nt], 0, 0, 0);
        }
      if (wave == 0) {  // boundary rows row0-16..row0-1 (xi only)
        bf16x8 ab = *(const bf16x8*)(&Asm[ks * 4 + quad][l16][0]);
        #pragma unroll
        for (int nt = 0; nt < NT; ++nt)
          acc2[nt] = __builtin_amdgcn_mfma_f32_16x16x32_bf16(ab, bx[nt],
                                                             acc2[nt], 0, 0, 0);
      }
    }
    __syncthreads();
  }

  // res epilogue (registers only)
  #pragma unroll
  for (int mt = 0; mt < 2; ++mt)
    #pragma unroll
    for (int nt = 0; nt < NT; ++nt) {
      int col   = c0x + nt * 16 + l16;
      int rbase = row0 + wave * 32 + mt * 16 + quad * 4;
      #pragma unroll
      for (int r = 0; r < 4; ++r)
        resbf[(size_t)(rbase + r) * DI + col] = f2bf(ar[mt][nt][r]);
    }

  // xi epilogue via LDS conv tile
  #pragma unroll
  for (int mt = 0; mt < 2; ++mt)
    #pragma unroll
    for (int nt = 0; nt < NT; ++nt)
      #pragma unroll
      for (int r = 0; r < 4; ++r)
        T[(3 + wave * 32 + mt * 16 + quad * 4 + r) * 68 + nt * 16 + l16] =
            ax[mt][nt][r];
  if (wave == 0 && quad == 3) {
    #pragma unroll
    for (int nt = 0; nt < NT; ++nt)
      #pragma unroll
      for (int r = 1; r < 4; ++r)  // boundary rows 13,14,15 -> T[0..2]
        T[(r - 1) * 68 + nt * 16 + l16] = acc2[nt][r];
  }
  __syncthreads();
  {
    const int c   = tid & 63;
    const int R0  = (tid >> 6) * 32;
    const int dch = c0x + c;
    float4 w4   = *(const float4*)(cw + dch * 4);
    float bias  = cb[dch];
    float t0 = T[(R0 + 0) * 68 + c];
    float t1 = T[(R0 + 1) * 68 + c];
    float t2 = T[(R0 + 2) * 68 + c];
    for (int rr = 0; rr < 32; ++rr) {
      float t3 = T[(R0 + rr + 3) * 68 + c];
      float s = fmaf(w4.x, t0, fmaf(w4.y, t1, fmaf(w4.z, t2, fmaf(w4.w, t3, bias))));
      float v = s / (1.f + __expf(-s));
      xcbf[(size_t)(row0 + R0 + rr) * DI + dch] = f2bf(v);
      t0 = t1; t1 = t2; t2 = t3;
    }
  }
}

// ---------------- fused scan: xproj MFMA + phase A + decoupled lookback ------
// ---------------- + replay + gated y2 + out_proj MFMA + residual -------------
// One block per (b, chunk), ordered by an atomic ticket so a block only ever
// spins on flags of earlier-started blocks (no dispatch-order assumption).
__global__ __launch_bounds__(512, 4) void scanF_kernel(
    const ushort_t* __restrict__ xcbf, const ushort_t* __restrict__ WbigT,
    const float* __restrict__ bdt, const float* __restrict__ Alog,
    const float* __restrict__ Dp, const ushort_t* __restrict__ resbf,
    const ushort_t* __restrict__ outWt, const float* __restrict__ x,
    float2* __restrict__ LOC, float* __restrict__ INC,
    unsigned int* __restrict__ syncb, float* __restrict__ out) {
  __shared__ __align__(16) ushort_t Asm[32][33][8];  // xc tile 16.9 KB
  __shared__ float T[32][257];                       // delta fp32 32.9 KB
  __shared__ float Bs[32][17], Cs[32][17];
  __shared__ __align__(16) ushort_t y2s[32][264];    // 16.9 KB
  __shared__ unsigned int vid_s;
  const int tid  = threadIdx.x;
  if (tid == 0) vid_s = atomicAdd(syncb, 1u);
  const int wave = tid >> 6, lane = tid & 63;
  const int quad = lane >> 4, l16 = lane & 15;
  const int d  = (wave << 5) | (lane & 31);
  const int nh = lane >> 5;
  const int n0 = nh * 8;
  __syncthreads();
  const unsigned int vid = vid_s;
  const int b = (int)(vid & 3u);       // 4 independent chains progress together
  const int c = (int)(vid >> 2);       // c strictly increasing in ticket order
  const int cid = (c << 2) | b;
  unsigned int* flags = syncb + 4;
  const size_t rowbase = (size_t)b * L_ + (size_t)c * CHUNK;

  {  // stage xc chunk tile (32 rows x 256 ch)
    int m = tid & 31, kb = tid >> 5;
    *(bf16x8*)(&Asm[kb][m][0]) =
        *(const bf16x8*)(xcbf + (rowbase + m) * DI + kb * 8);
    *(bf16x8*)(&Asm[kb + 16][m][0]) =
        *(const bf16x8*)(xcbf + (rowbase + m) * DI + (kb + 16) * 8);
  }
  __syncthreads();

  // xproj: 2 m-tiles x 18 n-tiles, K=256, B-frags streamed from L2
  for (int tp = wave; tp < 36; tp += 8) {
    int mt = tp / 18, nt = tp % 18;
    f32x4 acc = {0.f, 0.f, 0.f, 0.f};
    #pragma unroll
    for (int ks = 0; ks < 8; ++ks) {
      bf16x8 af = *(const bf16x8*)(&Asm[ks * 4 + quad][mt * 16 + l16][0]);
      bf16x8 bf = *(const bf16x8*)(WbigT + (size_t)(nt * 16 + l16) * DI + ks * 32 + quad * 8);
      acc = __builtin_amdgcn_mfma_f32_16x16x32_bf16(af, bf, acc, 0, 0, 0);
    }
    int row = mt * 16 + quad * 4;
    if (nt < 16) {
      int col = nt * 16 + l16;
      float bb = bdt[col];
      #pragma unroll
      for (int r = 0; r < 4; ++r) {
        float v = acc[r] + bb;
        T[row + r][col] = (v > 20.f) ? v : log1pf(__expf(v));  // softplus
      }
    } else if (nt == 16) {
      #pragma unroll
      for (int r = 0; r < 4; ++r) Bs[row + r][l16] = acc[r];
    } else {
      #pragma unroll
      for (int r = 0; r < 4; ++r) Cs[row + r][l16] = acc[r];
    }
  }
  __syncthreads();

  float c0 = -__expf(Alog[d * DS]) * LOG2E;
  float aln[8];
  #pragma unroll
  for (int j = 0; j < 8; ++j) aln[j] = -__expf(Alog[d * DS + n0 + j]) * LOG2E;
  bool geom = true;
  #pragma unroll
  for (int j = 0; j < 8; ++j)
    geom = geom && (fabsf(aln[j] - (n0 + j + 1) * c0) <= 1e-3f * fabsf(aln[j]));

  // ---- phase A: local chunk scan -> (P, S) in registers ----
  float P[8], S[8];
  #pragma unroll
  for (int j = 0; j < 8; ++j) { P[j] = 1.f; S[j] = 0.f; }
  for (int t = 0; t < CHUNK; ++t) {
    float dl = T[t][d];
    float xv = bf2f(Asm[d >> 3][t][d & 7]);
    float du = dl * xv;
    if (geom) {
      float e1 = exp2f(dl * c0);
      float a;
      if (nh) { float e2 = e1 * e1, e4 = e2 * e2; a = e4 * e4 * e1; }  // e1^9
      else a = e1;
      #pragma unroll
      for (int j = 0; j < 8; ++j) {
        P[j] *= a;
        S[j] = fmaf(a, S[j], du * Bs[t][n0 + j]);
        a *= e1;
      }
    } else {
      #pragma unroll
      for (int j = 0; j < 8; ++j) {
        float a = exp2f(dl * aln[j]);
        P[j] *= a;
        S[j] = fmaf(a, S[j], du * Bs[t][n0 + j]);
      }
    }
  }

  const size_t pbase = (size_t)((nh * 256 + d) << 3);  // 8 pairs per thread

  // ---- publish LOCAL summary (flag 1) ----
  if (c > 0) {
    float4* p4 = (float4*)(LOC + (((size_t)cid) << 12) + pbase);
    p4[0] = make_float4(P[0], S[0], P[1], S[1]);
    p4[1] = make_float4(P[2], S[2], P[3], S[3]);
    p4[2] = make_float4(P[4], S[4], P[5], S[5]);
    p4[3] = make_float4(P[6], S[6], P[7], S[7]);
    __threadfence();
    __syncthreads();
    if (tid == 0)
      __hip_atomic_store(&flags[cid], 1u, __ATOMIC_RELEASE, __HIP_MEMORY_SCOPE_AGENT);
  }

  // ---- decoupled lookback: fold predecessors until an INCLUSIVE is found ----
  float si[8];
  if (c > 0) {
    float Pa[8], Sa[8];
    #pragma unroll
    for (int j = 0; j < 8; ++j) { Pa[j] = 1.f; Sa[j] = 0.f; }
    int k = c - 1;
    for (;;) {
      unsigned int f;
      unsigned int* fp = &flags[(k << 2) | b];
      while ((f = __hip_atomic_load(fp, __ATOMIC_RELAXED, __HIP_MEMORY_SCOPE_AGENT)) == 0u)
        __builtin_amdgcn_s_sleep(1);
      __builtin_amdgcn_fence(__ATOMIC_ACQUIRE, "agent");
      const size_t cb = ((size_t)((k << 2) | b)) << 12;
      if (f == 2u) {  // inclusive prefix available: finish
        const float4* ip = (const float4*)(INC + cb + pbase);
        float4 i0 = ip[0], i1 = ip[1];
        si[0] = fmaf(Pa[0], i0.x, Sa[0]);  si[1] = fmaf(Pa[1], i0.y, Sa[1]);
        si[2] = fmaf(Pa[2], i0.z, Sa[2]);  si[3] = fmaf(Pa[3], i0.w, Sa[3]);
        si[4] = fmaf(Pa[4], i1.x, Sa[4]);  si[5] = fmaf(Pa[5], i1.y, Sa[5]);
        si[6] = fmaf(Pa[6], i1.z, Sa[6]);  si[7] = fmaf(Pa[7], i1.w, Sa[7]);
        break;
      }
      // fold LOCAL of chunk k:  g' = g o f_k
      const float4* lp = (const float4*)(LOC + cb + pbase);
      float4 q0 = lp[0], q1 = lp[1], q2 = lp[2], q3 = lp[3];
      Sa[0] = fmaf(Pa[0], q0.y, Sa[0]); Pa[0] *= q0.x;
      Sa[1] = fmaf(Pa[1], q0.w, Sa[1]); Pa[1] *= q0.z;
      Sa[2] = fmaf(Pa[2], q1.y, Sa[2]); Pa[2] *= q1.x;
      Sa[3] = fmaf(Pa[3], q1.w, Sa[3]); Pa[3] *= q1.z;
      Sa[4] = fmaf(Pa[4], q2.y, Sa[4]); Pa[4] *= q2.x;
      Sa[5] = fmaf(Pa[5], q2.w, Sa[5]); Pa[5] *= q2.z;
      Sa[6] = fmaf(Pa[6], q3.y, Sa[6]); Pa[6] *= q3.x;
      Sa[7] = fmaf(Pa[7], q3.w, Sa[7]); Pa[7] *= q3.z;
      if (--k < 0) {  // folded down to chunk 0: s_init = g(0)
        #pragma unroll
        for (int j = 0; j < 8; ++j) si[j] = Sa[j];
        break;
      }
    }
  } else {
    #pragma unroll
    for (int j = 0; j < 8; ++j) si[j] = 0.f;
  }

  // ---- publish INCLUSIVE prefix (flag 2); last chunk has no consumer ----
  if (c < NC - 1) {
    float4* ip = (float4*)(INC + (((size_t)cid) << 12) + pbase);
    ip[0] = make_float4(fmaf(P[0], si[0], S[0]), fmaf(P[1], si[1], S[1]),
                        fmaf(P[2], si[2], S[2]), fmaf(P[3], si[3], S[3]));
    ip[1] = make_float4(fmaf(P[4], si[4], S[4]), fmaf(P[5], si[5], S[5]),
                        fmaf(P[6], si[6], S[6]), fmaf(P[7], si[7], S[7]));
    __threadfence();
    __syncthreads();
    if (tid == 0)
      __hip_atomic_store(&flags[cid], 2u, __ATOMIC_RELEASE, __HIP_MEMORY_SCOPE_AGENT);
  }

  // ---- replay with true initial state (all operands still live in LDS) ----
  const float Dd = Dp[d];
  #pragma unroll
  for (int j = 0; j < 8; ++j) S[j] = si[j];
  for (int t = 0; t < CHUNK; ++t) {
    float dl = T[t][d];
    float xv = bf2f(Asm[d >> 3][t][d & 7]);
    float du = dl * xv;
    float y = 0.f;
    if (geom) {
      float e1 = exp2f(dl * c0);
      float a;
      if (nh) { float e2 = e1 * e1, e4 = e2 * e2; a = e4 * e4 * e1; }
      else a = e1;
      #pragma unroll
      for (int j = 0; j < 8; ++j) {
        S[j] = fmaf(a, S[j], du * Bs[t][n0 + j]);
        y = fmaf(S[j], Cs[t][n0 + j], y);
        a *= e1;
      }
    } else {
      #pragma unroll
      for (int j = 0; j < 8; ++j) {
        float a = exp2f(dl * aln[j]);
        S[j] = fmaf(a, S[j], du * Bs[t][n0 + j]);
        y = fmaf(S[j], Cs[t][n0 + j], y);
      }
    }
    float yo = __shfl_xor(y, 32);
    if (nh == 0) {
      float rv = bf2f(resbf[(rowbase + t) * DI + d]);
      float yt = y + yo + xv * Dd;
      float sil = rv / (1.f + __expf(-rv));
      y2s[t][d] = f2bf(yt * sil);
    }
  }
  __syncthreads();
  // out_proj: 32x256 (LDS) @ outWt[128][256]^T + x -> out 32x128
  #pragma unroll
  for (int mt = 0; mt < 2; ++mt) {
    f32x4 acc = {0.f, 0.f, 0.f, 0.f};
    #pragma unroll
    for (int ks = 0; ks < 8; ++ks) {
      bf16x8 af = *(const bf16x8*)(&y2s[mt * 16 + l16][ks * 32 + quad * 8]);
      bf16x8 bf = *(const bf16x8*)(outWt + (size_t)(wave * 16 + l16) * DI + ks * 32 + quad * 8);
      acc = __builtin_amdgcn_mfma_f32_16x16x32_bf16(af, bf, acc, 0, 0, 0);
    }
    int col = wave * 16 + l16;
    size_t rb = rowbase + mt * 16 + quad * 4;
    #pragma unroll
    for (int r = 0; r < 4; ++r)
      out[(rb + r) * DM + col] = acc[r] + x[(rb + r) * DM + col];
  }
}

extern "C" void kernel_launch(void* const* d_in, const int* in_sizes, int n_in,
                              void* d_out, int out_size, void* d_ws, size_t ws_size,
                              hipStream_t stream) {
  const float* x      = (const float*)d_in[0];
  const float* norm_w = (const float*)d_in[1];
  const float* inW    = (const float*)d_in[2];
  const float* convw  = (const float*)d_in[3];
  const float* convb  = (const float*)d_in[4];
  const float* xprojw = (const float*)d_in[5];
  const float* dtw    = (const float*)d_in[6];
  const float* dtb    = (const float*)d_in[7];
  const float* alog   = (const float*)d_in[8];
  const float* Dp     = (const float*)d_in[9];
  const float* outw   = (const float*)d_in[10];
  float* out = (float*)d_out;

  const size_t CS = (size_t)B_ * NC * DI * DS;   // 2,097,152 (d,n) pairs total
  float2* LOC   = (float2*)d_ws;                 // CS float2 (16 MB) local (P,S)
  float* INC    = (float*)(LOC + CS);            // CS floats (8 MB) inclusive
  unsigned int* syncb = (unsigned int*)(INC + CS);  // [0]=ticket, [4..515]=flags
  ushort_t* bfbase = (ushort_t*)(syncb + 1024);
  ushort_t* xbf    = bfbase;                        // M_*128
  ushort_t* xcbf   = xbf + (size_t)M_ * DM;         // M_*256
  ushort_t* resbf  = xcbf + (size_t)M_ * DI;        // M_*256
  ushort_t* inWt   = resbf + (size_t)M_ * DI;       // 512*128
  ushort_t* WbigT  = inWt + 512 * 128;              // 288*256
  ushort_t* outWt  = WbigT + NB * DI;               // 128*256

  prep_rms_kernel<<<M_ / 4 + (PREP_N + 255) / 256, 256, 0, stream>>>(
      x, norm_w, inW, xprojw, dtw, outw, xbf, inWt, WbigT, outWt, syncb);
  g1_conv_kernel<<<dim3(M_ / 128, 4), 256, 0, stream>>>(
      xbf, inWt, convw, convb, xcbf, resbf);
  scanF_kernel<<<B_ * NC, 512, 0, stream>>>(
      xcbf, WbigT, dtb, alog, Dp, resbf, outWt, x, LOC, INC, syncb, out);
}

// Round 3
// 256.802 us; speedup vs baseline: 3.7587x; 3.7587x over previous
//
#include <hip/hip_runtime.h>
#include <math.h>

#define B_    4
#define L_    4096
#define DM    128
#define DI    256
#define DS    16
#define DTR   8
#define XPN   (DTR + 2*DS)   // 40
#define NB    (DI + 2*DS)    // 288 fused xproj output cols
#define M_    (B_*L_)        // 16384
#define CHUNK 32
#define NC    (L_/CHUNK)     // 128
#define LOG2E 1.4426950408889634f
#define PREP_N (512*128 + NB*DI + DM*DI)   // 172032

typedef __attribute__((ext_vector_type(8))) short bf16x8;   // 8 bf16 = 4 VGPR
typedef __attribute__((ext_vector_type(4))) float f32x4;    // MFMA acc
typedef unsigned short ushort_t;

__device__ __forceinline__ ushort_t f2bf(float f) {  // fp32 -> bf16 RNE
  unsigned int u = __float_as_uint(f);
  u += 0x7FFFu + ((u >> 16) & 1u);
  return (ushort_t)(u >> 16);
}
__device__ __forceinline__ float bf2f(ushort_t u) {
  return __uint_as_float(((unsigned int)u) << 16);
}

// Single-use grid barrier over gridDim.x blocks (counter pre-zeroed by prep).
__device__ __forceinline__ void gbar(unsigned int* ctr, unsigned int nblk) {
  __syncthreads();
  if (threadIdx.x == 0) {
    __hip_atomic_fetch_add(ctr, 1u, __ATOMIC_ACQ_REL, __HIP_MEMORY_SCOPE_AGENT);
    while (__hip_atomic_load(ctr, __ATOMIC_RELAXED, __HIP_MEMORY_SCOPE_AGENT) < nblk)
      __builtin_amdgcn_s_sleep(4);
  }
  __syncthreads();
  __builtin_amdgcn_fence(__ATOMIC_ACQUIRE, "agent");
}

// ---------------- prep (weights->bf16 transposed, dtproj folded) + rmsnorm ----
// Also zeroes the two barrier counters (workspace poisoned between runs).
__global__ __launch_bounds__(256) void prep_rms_kernel(const float* __restrict__ x,
                                                       const float* __restrict__ nw,
                                                       const float* __restrict__ inW,
                                                       const float* __restrict__ Wx,
                                                       const float* __restrict__ Wdt,
                                                       const float* __restrict__ outw,
                                                       ushort_t* __restrict__ xbf,
                                                       ushort_t* __restrict__ inWt,
                                                       ushort_t* __restrict__ WbigT,
                                                       ushort_t* __restrict__ outWt,
                                                       unsigned int* __restrict__ syncb) {
  if (blockIdx.x == 0 && threadIdx.x < 8) syncb[threadIdx.x] = 0u;
  if (blockIdx.x < M_ / 4) {  // rmsnorm -> bf16
    int row  = blockIdx.x * 4 + (threadIdx.x >> 6);
    int lane = threadIdx.x & 63;
    const float* xp = x + (size_t)row * DM;
    float v0 = xp[lane], v1 = xp[lane + 64];
    float s = v0 * v0 + v1 * v1;
    #pragma unroll
    for (int off = 32; off > 0; off >>= 1) s += __shfl_xor(s, off);
    float r = rsqrtf(s / DM + 1e-5f);
    ushort_t* op = xbf + (size_t)row * DM;
    op[lane]      = f2bf(v0 * r * nw[lane]);
    op[lane + 64] = f2bf(v1 * r * nw[lane + 64]);
    return;
  }
  int g = (blockIdx.x - M_ / 4) * 256 + threadIdx.x;
  if (g < 512 * 128) {
    int n = g >> 7, k = g & 127;
    inWt[g] = f2bf(inW[k * 512 + n]);
  } else if (g < 512 * 128 + NB * DI) {
    int q = g - 512 * 128;
    int c = q >> 8, k = q & 255;
    float v;
    if (c < DI) {
      v = 0.f;
      #pragma unroll
      for (int j = 0; j < DTR; ++j) v = fmaf(Wx[k * XPN + j], Wdt[j * DI + c], v);
    } else {
      v = Wx[k * XPN + DTR + (c - DI)];
    }
    WbigT[q] = f2bf(v);
  } else if (g < PREP_N) {
    int q = g - (512 * 128 + NB * DI);
    int n = q >> 8, k = q & 255;
    outWt[q] = f2bf(outw[k * DM + n]);
  }
}

// ---------------- G1 fused: in_proj MFMA + depthwise conv + SiLU -------------
__global__ __launch_bounds__(256) void g1_conv_kernel(const ushort_t* __restrict__ A,
                                                      const ushort_t* __restrict__ Wt,
                                                      const float* __restrict__ cw,
                                                      const float* __restrict__ cb,
                                                      ushort_t* __restrict__ xcbf,
                                                      ushort_t* __restrict__ resbf) {
  constexpr int KK = 128, NT = 4;
  __shared__ __align__(16) char smem_raw[35648];
  ushort_t (*Asm)[145][8] = (ushort_t (*)[145][8])smem_raw;          // 18560 B
  ushort_t (*Bx)[65][8]   = (ushort_t (*)[65][8])(smem_raw + 18560); //  8320 B
  ushort_t (*Br)[65][8]   = (ushort_t (*)[65][8])(smem_raw + 26880); //  8320 B
  float* T = (float*)smem_raw;                                       // [131][68]
  const int tid  = threadIdx.x;
  const int wave = tid >> 6, lane = tid & 63;
  const int quad = lane >> 4, l16 = lane & 15;
  const int row0 = blockIdx.x * 128;
  const int by   = blockIdx.y;          // 0..3
  const int c0x  = by * 64;             // xi cols
  const int c0r  = 256 + by * 64;       // res cols (global N index)
  const bool zpad = (row0 & (L_ - 1)) == 0;
  f32x4 ax[2][NT], ar[2][NT], acc2[NT];
  #pragma unroll
  for (int mt = 0; mt < 2; ++mt)
    #pragma unroll
    for (int nt = 0; nt < NT; ++nt) {
      ax[mt][nt] = (f32x4){0.f, 0.f, 0.f, 0.f};
      ar[mt][nt] = (f32x4){0.f, 0.f, 0.f, 0.f};
    }
  #pragma unroll
  for (int nt = 0; nt < NT; ++nt) acc2[nt] = (f32x4){0.f, 0.f, 0.f, 0.f};

  for (int k0 = 0; k0 < KK; k0 += 64) {
    #pragma unroll
    for (int i = 0; i < 5; ++i) {  // A: 144 rows x 64 bf16 = 1152 b128
      int q = tid + i * 256;
      if (i < 4 || tid < 128) {
        int m = q >> 3, kb = q & 7;
        bf16x8 v = {0, 0, 0, 0, 0, 0, 0, 0};
        if (!(zpad && m < 16))
          v = *(const bf16x8*)(A + (size_t)(row0 - 16 + m) * KK + k0 + kb * 8);
        *(bf16x8*)(&Asm[kb][m][0]) = v;
      }
    }
    #pragma unroll
    for (int i = 0; i < 2; ++i) {  // B xi: 64x64 bf16
      int q = tid + i * 256;
      int n = q >> 3, kb = q & 7;
      *(bf16x8*)(&Bx[kb][n][0]) =
          *(const bf16x8*)(Wt + (size_t)(c0x + n) * KK + k0 + kb * 8);
    }
    #pragma unroll
    for (int i = 0; i < 2; ++i) {  // B res: 64x64 bf16
      int q = tid + i * 256;
      int n = q >> 3, kb = q & 7;
      *(bf16x8*)(&Br[kb][n][0]) =
          *(const bf16x8*)(Wt + (size_t)(c0r + n) * KK + k0 + kb * 8);
    }
    __syncthreads();
    #pragma unroll
    for (int ks = 0; ks < 2; ++ks) {
      bf16x8 af[2], bx[NT], br[NT];
      #pragma unroll
      for (int mt = 0; mt < 2; ++mt)
        af[mt] = *(const bf16x8*)(&Asm[ks * 4 + quad][16 + wave * 32 + mt * 16 + l16][0]);
      #pragma unroll
      for (int nt = 0; nt < NT; ++nt) {
        bx[nt] = *(const bf16x8*)(&Bx[ks * 4 + quad][nt * 16 + l16][0]);
        br[nt] = *(const bf16x8*)(&Br[ks * 4 + quad][nt * 16 + l16][0]);
      }
      #pragma unroll
      for (int mt = 0; mt < 2; ++mt)
        #pragma unroll
        for (int nt = 0; nt < NT; ++nt) {
          ax[mt][nt] = __builtin_amdgcn_mfma_f32_16x16x32_bf16(af[mt], bx[nt],
                                                               ax[mt][nt], 0, 0, 0);
          ar[mt][nt] = __builtin_amdgcn_mfma_f32_16x16x32_bf16(af[mt], br[nt],
                                                               ar[mt][nt], 0, 0, 0);
        }
      if (wave == 0) {  // boundary rows row0-16..row0-1 (xi only)
        bf16x8 ab = *(const bf16x8*)(&Asm[ks * 4 + quad][l16][0]);
        #pragma unroll
        for (int nt = 0; nt < NT; ++nt)
          acc2[nt] = __builtin_amdgcn_mfma_f32_16x16x32_bf16(ab, bx[nt],
                                                             acc2[nt], 0, 0, 0);
      }
    }
    __syncthreads();
  }

  // res epilogue (registers only)
  #pragma unroll
  for (int mt = 0; mt < 2; ++mt)
    #pragma unroll
    for (int nt = 0; nt < NT; ++nt) {
      int col   = c0x + nt * 16 + l16;
      int rbase = row0 + wave * 32 + mt * 16 + quad * 4;
      #pragma unroll
      for (int r = 0; r < 4; ++r)
        resbf[(size_t)(rbase + r) * DI + col] = f2bf(ar[mt][nt][r]);
    }

  // xi epilogue via LDS conv tile
  #pragma unroll
  for (int mt = 0; mt < 2; ++mt)
    #pragma unroll
    for (int nt = 0; nt < NT; ++nt)
      #pragma unroll
      for (int r = 0; r < 4; ++r)
        T[(3 + wave * 32 + mt * 16 + quad * 4 + r) * 68 + nt * 16 + l16] =
            ax[mt][nt][r];
  if (wave == 0 && quad == 3) {
    #pragma unroll
    for (int nt = 0; nt < NT; ++nt)
      #pragma unroll
      for (int r = 1; r < 4; ++r)  // boundary rows 13,14,15 -> T[0..2]
        T[(r - 1) * 68 + nt * 16 + l16] = acc2[nt][r];
  }
  __syncthreads();
  {
    const int c   = tid & 63;
    const int R0  = (tid >> 6) * 32;
    const int dch = c0x + c;
    float4 w4   = *(const float4*)(cw + dch * 4);
    float bias  = cb[dch];
    float t0 = T[(R0 + 0) * 68 + c];
    float t1 = T[(R0 + 1) * 68 + c];
    float t2 = T[(R0 + 2) * 68 + c];
    for (int rr = 0; rr < 32; ++rr) {
      float t3 = T[(R0 + rr + 3) * 68 + c];
      float s = fmaf(w4.x, t0, fmaf(w4.y, t1, fmaf(w4.z, t2, fmaf(w4.w, t3, bias))));
      float v = s / (1.f + __expf(-s));
      xcbf[(size_t)(row0 + R0 + rr) * DI + dch] = f2bf(v);
      t0 = t1; t1 = t2; t2 = t3;
    }
  }
}

// ---------------- fused scan: 256 blocks x 1024 thr, 2 chunks/block ----------
// half h owns chunk g = blockIdx + h*256, with its own LDS copy. Software
// barrier over 256 blocks (<= 1 block/CU fits under any placement).
__global__ __launch_bounds__(1024, 4) void scanF_kernel(
    const ushort_t* __restrict__ xcbf, const ushort_t* __restrict__ WbigT,
    const float* __restrict__ bdt, const float* __restrict__ Alog,
    const float* __restrict__ Dp, const ushort_t* __restrict__ resbf,
    const ushort_t* __restrict__ outWt, const float* __restrict__ x,
    float2* __restrict__ LOC, float* __restrict__ SIN,
    unsigned int* __restrict__ syncb, float* __restrict__ out) {
  __shared__ __align__(16) ushort_t Asm[2][32][33][8];  // 33.8 KB
  __shared__ float T[2][32][257];                       // 65.8 KB
  __shared__ float Bs[2][32][17], Cs[2][32][17];        //  8.7 KB
  __shared__ __align__(16) ushort_t y2s[2][32][264];    // 33.8 KB
  const int tid  = threadIdx.x;
  const int h    = tid >> 9;          // half id: which chunk
  const int t5   = tid & 511;
  const int wave = t5 >> 6, lane = t5 & 63;
  const int quad = lane >> 4, l16 = lane & 15;
  const int g = blockIdx.x + (h << 8);   // global chunk id 0..511
  const int b = g >> 7, c = g & (NC - 1);
  const size_t rowbase = (size_t)b * L_ + (size_t)c * CHUNK;
  const int d  = (wave << 5) | (lane & 31);
  const int nh = lane >> 5;
  const int n0 = nh * 8;

  {  // stage xc chunk tile (32 rows x 256 ch)
    int m = t5 & 31, kb = t5 >> 5;
    *(bf16x8*)(&Asm[h][kb][m][0]) =
        *(const bf16x8*)(xcbf + (rowbase + m) * DI + kb * 8);
    *(bf16x8*)(&Asm[h][kb + 16][m][0]) =
        *(const bf16x8*)(xcbf + (rowbase + m) * DI + (kb + 16) * 8);
  }
  __syncthreads();

  // xproj: 2 m-tiles x 18 n-tiles, K=256, B-frags streamed from L2
  for (int tp = wave; tp < 36; tp += 8) {
    int mt = tp / 18, nt = tp % 18;
    f32x4 acc = {0.f, 0.f, 0.f, 0.f};
    #pragma unroll
    for (int ks = 0; ks < 8; ++ks) {
      bf16x8 af = *(const bf16x8*)(&Asm[h][ks * 4 + quad][mt * 16 + l16][0]);
      bf16x8 bf = *(const bf16x8*)(WbigT + (size_t)(nt * 16 + l16) * DI + ks * 32 + quad * 8);
      acc = __builtin_amdgcn_mfma_f32_16x16x32_bf16(af, bf, acc, 0, 0, 0);
    }
    int row = mt * 16 + quad * 4;
    if (nt < 16) {
      int col = nt * 16 + l16;
      float bb = bdt[col];
      #pragma unroll
      for (int r = 0; r < 4; ++r) {
        float v = acc[r] + bb;
        T[h][row + r][col] = (v > 20.f) ? v : log1pf(__expf(v));  // softplus
      }
    } else if (nt == 16) {
      #pragma unroll
      for (int r = 0; r < 4; ++r) Bs[h][row + r][l16] = acc[r];
    } else {
      #pragma unroll
      for (int r = 0; r < 4; ++r) Cs[h][row + r][l16] = acc[r];
    }
  }
  __syncthreads();

  float c0 = -__expf(Alog[d * DS]) * LOG2E;
  float aln[8];
  #pragma unroll
  for (int j = 0; j < 8; ++j) aln[j] = -__expf(Alog[d * DS + n0 + j]) * LOG2E;
  bool geom = true;
  #pragma unroll
  for (int j = 0; j < 8; ++j)
    geom = geom && (fabsf(aln[j] - (n0 + j + 1) * c0) <= 1e-3f * fabsf(aln[j]));

  // ---- phase A: local chunk scan -> (P, S) in registers ----
  float P[8], S[8];
  #pragma unroll
  for (int j = 0; j < 8; ++j) { P[j] = 1.f; S[j] = 0.f; }
  for (int t = 0; t < CHUNK; ++t) {
    float dl = T[h][t][d];
    float xv = bf2f(Asm[h][d >> 3][t][d & 7]);
    float du = dl * xv;
    if (geom) {
      float e1 = exp2f(dl * c0);
      float a;
      if (nh) { float e2 = e1 * e1, e4 = e2 * e2; a = e4 * e4 * e1; }  // e1^9
      else a = e1;
      #pragma unroll
      for (int j = 0; j < 8; ++j) {
        P[j] *= a;
        S[j] = fmaf(a, S[j], du * Bs[h][t][n0 + j]);
        a *= e1;
      }
    } else {
      #pragma unroll
      for (int j = 0; j < 8; ++j) {
        float a = exp2f(dl * aln[j]);
        P[j] *= a;
        S[j] = fmaf(a, S[j], du * Bs[h][t][n0 + j]);
      }
    }
  }

  // ---- publish local (P,S) summaries ----
  const size_t pbase = (size_t)((nh * 256 + d) << 3);  // 8 pairs per thread
  {
    float4* p4 = (float4*)(LOC + (((size_t)g) << 12) + pbase);
    p4[0] = make_float4(P[0], S[0], P[1], S[1]);
    p4[1] = make_float4(P[2], S[2], P[3], S[3]);
    p4[2] = make_float4(P[4], S[4], P[5], S[5]);
    p4[3] = make_float4(P[6], S[6], P[7], S[7]);
  }
  gbar(&syncb[0], 256);

  // ---- phase B: serial scan over chunk summaries, 64 chains per block ----
  if (tid < 64) {
    int gch = blockIdx.x * 64 + tid;    // 0..16383 = b*4096 + dn
    int bB = gch >> 12, dn = gch & 4095;
    float s = 0.f;
    #pragma unroll 16
    for (int cc = 0; cc < NC; ++cc) {
      size_t idx = ((size_t)(bB * NC + cc) << 12) + (size_t)dn;
      SIN[idx] = s;
      float2 v = LOC[idx];
      s = fmaf(v.x, s, v.y);
    }
  }
  gbar(&syncb[1], 256);

  // ---- phase C: replay with true initial state (LDS operands still live) ----
  {
    size_t ib = (((size_t)g) << 12) + pbase;
    float4 v0 = *(const float4*)(SIN + ib);
    float4 v1 = *(const float4*)(SIN + ib + 4);
    S[0] = v0.x; S[1] = v0.y; S[2] = v0.z; S[3] = v0.w;
    S[4] = v1.x; S[5] = v1.y; S[6] = v1.z; S[7] = v1.w;
  }
  const float Dd = Dp[d];
  for (int t = 0; t < CHUNK; ++t) {
    float dl = T[h][t][d];
    float xv = bf2f(Asm[h][d >> 3][t][d & 7]);
    float du = dl * xv;
    float y = 0.f;
    if (geom) {
      float e1 = exp2f(dl * c0);
      float a;
      if (nh) { float e2 = e1 * e1, e4 = e2 * e2; a = e4 * e4 * e1; }
      else a = e1;
      #pragma unroll
      for (int j = 0; j < 8; ++j) {
        S[j] = fmaf(a, S[j], du * Bs[h][t][n0 + j]);
        y = fmaf(S[j], Cs[h][t][n0 + j], y);
        a *= e1;
      }
    } else {
      #pragma unroll
      for (int j = 0; j < 8; ++j) {
        float a = exp2f(dl * aln[j]);
        S[j] = fmaf(a, S[j], du * Bs[h][t][n0 + j]);
        y = fmaf(S[j], Cs[h][t][n0 + j], y);
      }
    }
    float yo = __shfl_xor(y, 32);
    if (nh == 0) {
      float rv = bf2f(resbf[(rowbase + t) * DI + d]);
      float yt = y + yo + xv * Dd;
      float sil = rv / (1.f + __expf(-rv));
      y2s[h][t][d] = f2bf(yt * sil);
    }
  }
  __syncthreads();
  // out_proj: 32x256 (LDS) @ outWt[128][256]^T + x -> out 32x128
  #pragma unroll
  for (int mt = 0; mt < 2; ++mt) {
    f32x4 acc = {0.f, 0.f, 0.f, 0.f};
    #pragma unroll
    for (int ks = 0; ks < 8; ++ks) {
      bf16x8 af = *(const bf16x8*)(&y2s[h][mt * 16 + l16][ks * 32 + quad * 8]);
      bf16x8 bf = *(const bf16x8*)(outWt + (size_t)(wave * 16 + l16) * DI + ks * 32 + quad * 8);
      acc = __builtin_amdgcn_mfma_f32_16x16x32_bf16(af, bf, acc, 0, 0, 0);
    }
    int col = wave * 16 + l16;
    size_t rb = rowbase + mt * 16 + quad * 4;
    #pragma unroll
    for (int r = 0; r < 4; ++r)
      out[(rb + r) * DM + col] = acc[r] + x[(rb + r) * DM + col];
  }
}

extern "C" void kernel_launch(void* const* d_in, const int* in_sizes, int n_in,
                              void* d_out, int out_size, void* d_ws, size_t ws_size,
                              hipStream_t stream) {
  const float* x      = (const float*)d_in[0];
  const float* norm_w = (const float*)d_in[1];
  const float* inW    = (const float*)d_in[2];
  const float* convw  = (const float*)d_in[3];
  const float* convb  = (const float*)d_in[4];
  const float* xprojw = (const float*)d_in[5];
  const float* dtw    = (const float*)d_in[6];
  const float* dtb    = (const float*)d_in[7];
  const float* alog   = (const float*)d_in[8];
  const float* Dp     = (const float*)d_in[9];
  const float* outw   = (const float*)d_in[10];
  float* out = (float*)d_out;

  const size_t CS = (size_t)B_ * NC * DI * DS;   // 2,097,152 (d,n) pairs total
  float2* LOC   = (float2*)d_ws;                 // CS float2 (16 MB) local (P,S)
  float* SIN    = (float*)(LOC + CS);            // CS floats (8 MB) s_init
  unsigned int* syncb = (unsigned int*)(SIN + CS);  // barrier counters
  ushort_t* bfbase = (ushort_t*)(syncb + 1024);
  ushort_t* xbf    = bfbase;                        // M_*128
  ushort_t* xcbf   = xbf + (size_t)M_ * DM;         // M_*256
  ushort_t* resbf  = xcbf + (size_t)M_ * DI;        // M_*256
  ushort_t* inWt   = resbf + (size_t)M_ * DI;       // 512*128
  ushort_t* WbigT  = inWt + 512 * 128;              // 288*256
  ushort_t* outWt  = WbigT + NB * DI;               // 128*256

  prep_rms_kernel<<<M_ / 4 + (PREP_N + 255) / 256, 256, 0, stream>>>(
      x, norm_w, inW, xprojw, dtw, outw, xbf, inWt, WbigT, outWt, syncb);
  g1_conv_kernel<<<dim3(M_ / 128, 4), 256, 0, stream>>>(
      xbf, inWt, convw, convb, xcbf, resbf);
  scanF_kernel<<<256, 1024, 0, stream>>>(
      xcbf, WbigT, dtb, alog, Dp, resbf, outWt, x, LOC, SIN, syncb, out);
}